// Round 1
// 704.821 us; speedup vs baseline: 1.0046x; 1.0046x over previous
//
#include <hip/hip_runtime.h>
#include <math.h>

// Problem constants (B,S,H fixed by reference setup_inputs)
#define BB 32
#define SS 4096
#define HH 1024
#define NCHUNK 64               // grid 64*32 = 2048 blocks (8/CU wanted, ~4 resident)
#define CHUNK (SS / NCHUNK)     // 64 s-rows per block, 16 per wave, 8 pair-iterations
#define NSPLIT 4                // combine: split H across 4 blocks per batch
#define NEG_INF9 (-1.0e9f)

// ---------------------------------------------------------------------------
// Wave64 all-reduce(sum) via DPP tree — pure VALU (~8 cy/step) instead of the
// 6-step ds_bpermute butterfly (~120 cy/step serial). Result is returned via
// readlane -> SGPR, so downstream softmax state is wave-uniform scalar.
//   row_shr:1,2,4,8  -> lane 15/31/47/63 hold their row-of-16 sums
//   row_bcast:15     -> lane 31 = sum(lanes 0..31)
//   row_bcast:31     -> lane 63 = sum(lanes 0..63)
// ---------------------------------------------------------------------------
__device__ __forceinline__ float dpp_allreduce_add(float x) {
    int t;
    t = __builtin_amdgcn_update_dpp(0, __float_as_int(x), 0x111, 0xf, 0xf, false); // row_shr:1
    x += __int_as_float(t);
    t = __builtin_amdgcn_update_dpp(0, __float_as_int(x), 0x112, 0xf, 0xf, false); // row_shr:2
    x += __int_as_float(t);
    t = __builtin_amdgcn_update_dpp(0, __float_as_int(x), 0x114, 0xf, 0xf, false); // row_shr:4
    x += __int_as_float(t);
    t = __builtin_amdgcn_update_dpp(0, __float_as_int(x), 0x118, 0xf, 0xf, false); // row_shr:8
    x += __int_as_float(t);
    t = __builtin_amdgcn_update_dpp(0, __float_as_int(x), 0x142, 0xf, 0xf, false); // row_bcast:15
    x += __int_as_float(t);
    t = __builtin_amdgcn_update_dpp(0, __float_as_int(x), 0x143, 0xf, 0xf, false); // row_bcast:31
    x += __int_as_float(t);
    return __int_as_float(__builtin_amdgcn_readlane(__float_as_int(x), 63));
}

// ---------------- Kernel 1: q = query @ W^T ----------------
__global__ __launch_bounds__(256) void qproj_kernel(const float* __restrict__ query,
                                                    const float* __restrict__ W,
                                                    float* __restrict__ q) {
    const int b    = blockIdx.y;
    const int wave = threadIdx.x >> 6;
    const int lane = threadIdx.x & 63;

    const float4* qp = (const float4*)(query + (size_t)b * HH);
    float4 qv[4];
#pragma unroll
    for (int r = 0; r < 4; ++r) qv[r] = qp[r * 64 + lane];

    const int obase = blockIdx.x * 64 + wave * 16;
    for (int i = 0; i < 16; ++i) {
        const int o = obase + i;
        const float4* wp = (const float4*)(W + (size_t)o * HH);
        float acc = 0.f;
#pragma unroll
        for (int r = 0; r < 4; ++r) {
            const float4 wv = wp[r * 64 + lane];
            acc += wv.x * qv[r].x + wv.y * qv[r].y + wv.z * qv[r].z + wv.w * qv[r].w;
        }
        const float s = dpp_allreduce_add(acc);
        if (lane == 0) q[(size_t)b * HH + o] = s;
    }
}

// ---------------- Kernel 2: fused scores+softmax+context partials ----------------
// Per wave: 16 key rows as 8 explicitly double-buffered row-pair iterations.
//  - prefetch of pair i+1 (8x global_load_dwordx4 + mask int2) issues BEFORE the
//    reduce/softmax chain of pair i -> 8 KB always in flight per wave.
//  - DPP reduce + readlane makes sc/m/l/p wave-uniform scalars; acc rescale is a
//    uniform branch taken only when the running max actually moves (exact: e^0=1).
__global__ __launch_bounds__(256) void attn_chunk_kernel(const float* __restrict__ q,
                                                         const float* __restrict__ keys,
                                                         const int* __restrict__ mask,
                                                         float* __restrict__ raw_scores,
                                                         float* __restrict__ pm,
                                                         float* __restrict__ pl,
                                                         float* __restrict__ pO) {
    const int b    = blockIdx.y;
    const int c    = blockIdx.x;
    const int wave = threadIdx.x >> 6;
    const int lane = threadIdx.x & 63;

    const float4* qp = (const float4*)(q + (size_t)b * HH);
    float4 qv[4];
#pragma unroll
    for (int r = 0; r < 4; ++r) qv[r] = qp[r * 64 + lane];

    const size_t bbase = (size_t)b * SS;
    const int s0 = c * CHUNK + wave * 2;                  // this wave's first row pair; stride 8
    // float4 view: one key row = 256 float4
    const float4* kbase = (const float4*)(keys + (bbase + s0) * HH) + lane;

    float4 ka[2][4], kb[2][4];
    int2   mk[2];

    // prologue: load pair 0
    {
        const float4* p0 = kbase;
        const float4* p1 = kbase + 256;
#pragma unroll
        for (int r = 0; r < 4; ++r) { ka[0][r] = p0[r * 64]; kb[0][r] = p1[r * 64]; }
        mk[0] = *(const int2*)(mask + bbase + s0);
    }

    float m = -INFINITY;
    float l = 0.f;
    float4 acc[4];
#pragma unroll
    for (int r = 0; r < 4; ++r) acc[r] = make_float4(0.f, 0.f, 0.f, 0.f);

#pragma unroll
    for (int i = 0; i < CHUNK / 8; ++i) {
        const int cur = i & 1, nxt = cur ^ 1;
        // ---- prefetch pair i+1 (in flight across the whole chain below)
        if (i + 1 < CHUNK / 8) {
            const float4* p0 = kbase + (size_t)(i + 1) * 8 * 256;
            const float4* p1 = p0 + 256;
#pragma unroll
            for (int r = 0; r < 4; ++r) { ka[nxt][r] = p0[r * 64]; kb[nxt][r] = p1[r * 64]; }
            mk[nxt] = *(const int2*)(mask + bbase + s0 + 8 * (i + 1));
        }

        // ---- dot products for current pair
        float x0 = 0.f, x1 = 0.f;
#pragma unroll
        for (int r = 0; r < 4; ++r) {
            x0 += ka[cur][r].x * qv[r].x + ka[cur][r].y * qv[r].y + ka[cur][r].z * qv[r].z + ka[cur][r].w * qv[r].w;
            x1 += kb[cur][r].x * qv[r].x + kb[cur][r].y * qv[r].y + kb[cur][r].z * qv[r].z + kb[cur][r].w * qv[r].w;
        }
        float sc0 = dpp_allreduce_add(x0);   // wave-uniform (SGPR)
        float sc1 = dpp_allreduce_add(x1);

        const int mx = __builtin_amdgcn_readfirstlane(mk[cur].x);
        const int my = __builtin_amdgcn_readfirstlane(mk[cur].y);
        if (mx != 0) sc0 = NEG_INF9;
        if (my != 0) sc1 = NEG_INF9;
        if (lane == 0) *(float2*)(raw_scores + bbase + s0 + 8 * i) = make_float2(sc0, sc1);

        const float mnew = fmaxf(m, fmaxf(sc0, sc1));
        if (mnew > m) {                       // uniform scalar branch; exact (skip <=> scale==1)
            const float scale = __expf(m - mnew);   // m=-inf first iter -> 0
            l *= scale;
#pragma unroll
            for (int r = 0; r < 4; ++r) {
                acc[r].x *= scale; acc[r].y *= scale; acc[r].z *= scale; acc[r].w *= scale;
            }
            m = mnew;
        }
        const float p0 = __expf(sc0 - m);
        const float p1 = __expf(sc1 - m);
        l += p0 + p1;
#pragma unroll
        for (int r = 0; r < 4; ++r) {
            acc[r].x += p0 * ka[cur][r].x + p1 * kb[cur][r].x;
            acc[r].y += p0 * ka[cur][r].y + p1 * kb[cur][r].y;
            acc[r].z += p0 * ka[cur][r].z + p1 * kb[cur][r].z;
            acc[r].w += p0 * ka[cur][r].w + p1 * kb[cur][r].w;
        }
    }

    // ---- combine the 4 waves of this block via LDS
    __shared__ float  sm[4];
    __shared__ float  sl[4];
    __shared__ float4 sO[4][256];  // 16 KB
#pragma unroll
    for (int r = 0; r < 4; ++r) sO[wave][r * 64 + lane] = acc[r];
    if (lane == 0) { sm[wave] = m; sl[wave] = l; }
    __syncthreads();

    const float M = fmaxf(fmaxf(sm[0], sm[1]), fmaxf(sm[2], sm[3]));
    float f[4];
#pragma unroll
    for (int w = 0; w < 4; ++w) f[w] = __expf(sm[w] - M);
    const float L = sl[0] * f[0] + sl[1] * f[1] + sl[2] * f[2] + sl[3] * f[3];

    const int tid = threadIdx.x;
    float4 o = make_float4(0.f, 0.f, 0.f, 0.f);
#pragma unroll
    for (int w = 0; w < 4; ++w) {
        const float4 v = sO[w][tid];
        o.x += f[w] * v.x; o.y += f[w] * v.y; o.z += f[w] * v.z; o.w += f[w] * v.w;
    }
    ((float4*)(pO + ((size_t)b * NCHUNK + c) * HH))[tid] = o;
    if (tid == 0) { pm[b * NCHUNK + c] = M; pl[b * NCHUNK + c] = L; }
}

// ---------------- Kernel 3: merge chunk partials -> context; normalize weights ----------------
// grid (NSPLIT, BB): each block owns a 256-float slice of H and a 1024-entry slice of S.
__global__ __launch_bounds__(256) void combine_kernel(const float* __restrict__ pm,
                                                      const float* __restrict__ pl,
                                                      const float* __restrict__ pO,
                                                      float* __restrict__ context,
                                                      float* __restrict__ weights) {
    const int b    = blockIdx.y;
    const int part = blockIdx.x;
    const int tid  = threadIdx.x;

    float M = -INFINITY;
#pragma unroll 8
    for (int cc = 0; cc < NCHUNK; ++cc) M = fmaxf(M, pm[b * NCHUNK + cc]);
    float L = 0.f;
#pragma unroll 8
    for (int cc = 0; cc < NCHUNK; ++cc) L += pl[b * NCHUNK + cc] * __expf(pm[b * NCHUNK + cc] - M);
    const float invL = 1.f / L;

    // context slice: 256 consecutive floats (coalesced per chunk read)
    const int h = part * 256 + tid;
    float o = 0.f;
#pragma unroll 8
    for (int cc = 0; cc < NCHUNK; ++cc)
        o += __expf(pm[b * NCHUNK + cc] - M) * pO[((size_t)b * NCHUNK + cc) * HH + h];
    context[(size_t)b * HH + h] = o * invL;

    // weights slice: raw (masked) scores -> normalized softmax; masked -1e9 -> exactly 0
    const int sbeg = part * (SS / NSPLIT);
    for (int s = sbeg + tid; s < sbeg + SS / NSPLIT; s += 256) {
        const float sc = weights[(size_t)b * SS + s];
        weights[(size_t)b * SS + s] = __expf(sc - M) * invL;
    }
}

extern "C" void kernel_launch(void* const* d_in, const int* in_sizes, int n_in,
                              void* d_out, int out_size, void* d_ws, size_t ws_size,
                              hipStream_t stream) {
    const float* query = (const float*)d_in[0];  // [B,1,H]
    const float* keys  = (const float*)d_in[1];  // [B,S,H]
    const int*   mask  = (const int*)d_in[2];    // [B,S] bool->int
    const float* W     = (const float*)d_in[3];  // [H,H]

    float* context = (float*)d_out;                     // B*H floats
    float* weights = (float*)d_out + (size_t)BB * HH;   // B*S floats

    float* q  = (float*)d_ws;                    // B*H
    float* pm = q + (size_t)BB * HH;             // B*NCHUNK
    float* pl = pm + BB * NCHUNK;                // B*NCHUNK
    float* pO = pl + BB * NCHUNK;                // B*NCHUNK*H (8 MB)

    qproj_kernel<<<dim3(HH / 64, BB), 256, 0, stream>>>(query, W, q);
    attn_chunk_kernel<<<dim3(NCHUNK, BB), 256, 0, stream>>>(q, keys, mask, weights, pm, pl, pO);
    combine_kernel<<<dim3(NSPLIT, BB), 256, 0, stream>>>(pm, pl, pO, context, weights);
}